// Round 5
// baseline (256.261 us; speedup 1.0000x reference)
//
#include <hip/hip_runtime.h>

// Problem constants (fixed by setup_inputs)
constexpr int Bn = 128, Cn = 3, Sn = 256;
constexpr int HWn = Sn * Sn;          // 65536
constexpr int NPLANE = Bn * Cn;       // 384
constexpr float DTf = 0.05f;
constexpr float EPSf = 1e-6f;
constexpr float MAXCf = 1.0f;

// ws float layout:
//   [8..25]     r[step][dir][c] (18)
//   [32..127]   means partials (6 groups x 16 blocks)
//   [128..]     cp tables [18][256] (cp[255] = TRUE value)
//   [4736..]    dinv tables [18][256]
#define WS_R    8
#define WS_PART 32
#define WS_CP   128
#define WS_DINV 4736

__global__ void means_part(const float* __restrict__ aspat,
                           const float* __restrict__ bspat,
                           float* __restrict__ ws) {
  int grp = blockIdx.x >> 4;   // 0..5 = dir*3 + c
  int sub = blockIdx.x & 15;
  const float* base = (grp < 3) ? (aspat + grp * HWn) : (bspat + (grp - 3) * HWn);
  const float4* p = (const float4*)base + sub * 1024 + threadIdx.x;
  double acc = 0.0;
#pragma unroll
  for (int k = 0; k < 4; ++k) {
    float4 v = p[k * 256];
    acc += (double)v.x + (double)v.y + (double)v.z + (double)v.w;
  }
  __shared__ double sm[256];
  sm[threadIdx.x] = acc;
  __syncthreads();
  for (int s = 128; s > 0; s >>= 1) {
    if (threadIdx.x < s) sm[threadIdx.x] += sm[threadIdx.x + s];
    __syncthreads();
  }
  if (threadIdx.x == 0) ws[WS_PART + blockIdx.x] = (float)sm[0];
}

// One thread per (step, dir, channel): build cp[256], dinv[256], r.
__global__ void coeff_kernel(const float* __restrict__ alpha_base,
                             const float* __restrict__ beta_base,
                             float* __restrict__ ws) {
  int id = threadIdx.x;
  if (id >= 18) return;
  int s = id / 6, dir = (id / 3) % 2, c = id % 3;
  double msum = 0.0;
  for (int k = 0; k < 16; ++k) msum += (double)ws[WS_PART + (dir * 3 + c) * 16 + k];
  float mean = (float)(msum * (1.0 / HWn));
  float t = (float)s * DTf;
  float base = (dir == 0) ? alpha_base[c] : beta_base[c];
  float coef = fminf(fmaxf(base + mean * t, EPSf), MAXCf);
  float r = coef * (DTf * 0.5f);  // DX = 1
  ws[WS_R + id] = r;
  float* cp = ws + WS_CP + id * 256;
  float* dinv = ws + WS_DINV + id * 256;
  float b0 = 1.0f + r;
  float bi = 1.0f + 2.0f * r;
  dinv[0] = 1.0f / (b0 + EPSf);
  cp[0] = -r / (b0 + EPSf);
  for (int i = 1; i < 256; ++i) {
    float b = (i == 255) ? b0 : bi;
    float denom = fmaxf(b + r * cp[i - 1], EPSf);  // b - a*cp_prev, a=-r
    cp[i] = -r / denom;
    dinv[i] = 1.0f / denom;
  }
  // cp[255] TRUE: forward uses -cp[i]==r*dinv[i] at all i; back-substitution
  // never multiplies cp[255] (x_255 = dp_255 explicitly).
}

// ------------- Fully-fused kernel: 3 ADI steps (6 solves) in one pass -------
// Block = (plane, stripe): 112-row x 256-col LDS window, core 64 rows.
// Row validity shrinks 8/side per y-solve (halo-truncation, err ~0.0075^9).
// diag(coupling) is applied to the field at the END of EVERY step (matches
// reference: u = uy * diag per step).
// LDS swizzle (involution, quad-granular): (row,col) at word
//   row*256 + ((colq ^ (row&7))<<2 | col&3).
__global__ __launch_bounds__(1024) void fused3(
    const float* __restrict__ src, float* __restrict__ dst,
    const float* __restrict__ ws, const float* __restrict__ coupling) {
  __shared__ float tile[112 * 256];          // 112 KiB
  __shared__ float s_cp[6][256];             // [step*2 + dir]
  __shared__ float s_di[6][256];
  __shared__ float s_diag;

  const int t = threadIdx.x;
  // XCD-bijective swizzle: 1536 = 8*192; same-plane stripes -> same XCD.
  const int logical = (blockIdx.x & 7) * 192 + (blockIdx.x >> 3);
  const int plane = logical >> 2;            // b*3 + c
  const int s = logical & 3;                 // stripe
  const int c = plane % 3;

  const int base = s * 64;
  const int a0 = (s == 0) ? 0 : base - 24;
  const int b0 = (s == 3) ? 256 : base + 88;
  const int W = b0 - a0;                     // 112 interior, 88 edges

  // ---- issue DMA: wave wv owns rows [8wv, 8wv+8) (same rows it x0-solves) --
  const float* srcp = src + (size_t)plane * HWn;
  {
    const int wv = t >> 6, l = t & 63;
    const int r0 = wv * 8;
    if (r0 < W) {
#pragma unroll
      for (int k = 0; k < 8; ++k) {
        const int rl = r0 + k;
        const float* gp = srcp + (size_t)(a0 + rl) * 256 + ((l ^ (rl & 7)) << 2);
        __builtin_amdgcn_global_load_lds(
            (const __attribute__((address_space(1))) void*)gp,
            (__attribute__((address_space(3))) void*)(tile + rl * 256), 16, 0, 0);
      }
    }
  }

  // ---- coefficient tables -> LDS (waves 0..11), diag ----
  if (t < 384) {                              // cp: 6 tables x 64 float4
    const int tab = t >> 6, q = t & 63;
    const int id = (tab >> 1) * 6 + (tab & 1) * 3 + c;
    ((float4*)s_cp[tab])[q] = ((const float4*)(ws + WS_CP + id * 256))[q];
  } else if (t < 768) {                       // dinv
    const int u = t - 384;
    const int tab = u >> 6, q = u & 63;
    const int id = (tab >> 1) * 6 + (tab & 1) * 3 + c;
    ((float4*)s_di[tab])[q] = ((const float4*)(ws + WS_DINV + id * 256))[q];
  } else if (t == 768) {
    s_diag = coupling[c * 3 + c];
  }

  // Barrier for tables only (lgkm); DMA stays in flight (per-wave vmcnt later).
  asm volatile("s_waitcnt lgkmcnt(0)" ::: "memory");
  __builtin_amdgcn_s_barrier();
  __builtin_amdgcn_sched_barrier(0);

#pragma unroll
  for (int k = 0; k < 3; ++k) {
    // ================= x-solve (row-local, all W rows) =================
    {
      if (k == 0) asm volatile("s_waitcnt vmcnt(0)" ::: "memory");  // own rows
      const int rw = t >> 3, cw = t & 7;
      if (rw < W) {                           // wave-uniform (W % 8 == 0)
        // chunk col-window: 13 quads starting at qs; core quads [8cw,8cw+8)
        // qs mod 8 spread so a wave's 8 chunks are <=2-way on LDS bank groups
        const int off = (cw == 0) ? 0 : ((cw == 7) ? 5 : ((cw <= 4) ? cw : cw - 4));
        const int qs = 8 * cw - off;          // core at rel [off, off+8)
        const int sw = rw & 7;
        float4* trow = (float4*)tile + rw * 64;
        const float4* cp4 = (const float4*)s_cp[2 * k];
        const float4* di4 = (const float4*)s_di[2 * k];
        float4 dq[13];
        float prev = 0.0f;                    // exact at col 0; halo-trunc else
#pragma unroll
        for (int i = 0; i < 13; ++i) {
          const int q = qs + i;
          float4 v = trow[q ^ sw];
          float4 cq = cp4[q];
          float4 eq = di4[q];
          float d0 = fmaf(-cq.x, prev, v.x * eq.x);
          float d1 = fmaf(-cq.y, d0, v.y * eq.y);
          float d2 = fmaf(-cq.z, d1, v.z * eq.z);
          float d3 = fmaf(-cq.w, d2, v.w * eq.w);
          dq[i] = make_float4(d0, d1, d2, d3);
          prev = d3;
        }
        float x = 0.0f;
#pragma unroll
        for (int i = 12; i >= 0; --i) {
          const int q = qs + i;
          float4 v = dq[i];
          float4 cq = cp4[q];
          float x3 = (i == 12) ? v.w : fmaf(-cq.w, x, v.w);
          float x2 = fmaf(-cq.z, x3, v.z);
          float x1 = fmaf(-cq.y, x2, v.y);
          float x0 = fmaf(-cq.x, x1, v.x);
          if (i >= off && i < off + 8) trow[q ^ sw] = make_float4(x0, x1, x2, x3);
          x = x0;
        }
      }
      __syncthreads();
    }
    // ================= y-solve (4 halo-truncated segments/column) ==========
    {
      const int col = t & 255, seg = t >> 8;  // seg wave-uniform
      const int av = (s == 0) ? 0 : a0 + 8 * k;
      const int bv = (s == 3) ? 256 : b0 - 8 * k;
      const int o0 = (s == 0) ? 0 : a0 + 8 * (k + 1);
      const int o1 = (s == 3) ? 256 : b0 - 8 * (k + 1);
      const int clen = (o1 - o0) >> 2;        // {24,20,16} / {20,18,16}
      const int c0 = o0 + seg * clen, c1 = c0 + clen;
      const int hs = (c0 - 8 > av) ? (c0 - 8) : av;
      const int he = (c1 + 8 < bv) ? (c1 + 8) : bv;
      const float* cpy = s_cp[2 * k + 1];
      const float* diy = s_di[2 * k + 1];
      const int jq = col >> 2, jr = col & 3;
      float dp[40];
      float prev = 0.0f;                      // exact at row 0; halo-trunc else
#pragma unroll
      for (int i = 0; i < 40; ++i) {
        const int h = hs + i;
        const bool in = (h < he);
        const int rl = (in ? h : (he - 1)) - a0;
        float v = tile[rl * 256 + (((jq ^ (rl & 7)) << 2) | jr)];
        const int ht = in ? h : 255;
        float nd = fmaf(-cpy[ht], prev, v * diy[ht]);
        dp[i] = nd;
        prev = in ? nd : prev;
      }
      __syncthreads();                        // all fwd reads before bwd writes
      float x = 0.0f;
      const float dg = s_diag;
      if (k == 2) {
        float* dstp = dst + (size_t)plane * HWn + col;
#pragma unroll
        for (int i = 39; i >= 0; --i) {
          const int h = hs + i;
          if (h < he) {
            x = (h == he - 1) ? dp[i] : fmaf(-cpy[h], x, dp[i]);
            if (h >= c0 && h < c1) dstp[(size_t)h * 256] = x * dg;
          }
        }
      } else {
        // diag applies to the field after EVERY step (reference: u = uy*diag);
        // the back-substitution recurrence itself stays unscaled.
#pragma unroll
        for (int i = 39; i >= 0; --i) {
          const int h = hs + i;
          if (h < he) {
            x = (h == he - 1) ? dp[i] : fmaf(-cpy[h], x, dp[i]);
            if (h >= c0 && h < c1) {
              const int rl = h - a0;
              tile[rl * 256 + (((jq ^ (rl & 7)) << 2) | jr)] = x * dg;
            }
          }
        }
        __syncthreads();
      }
    }
  }
}

extern "C" void kernel_launch(void* const* d_in, const int* in_sizes, int n_in,
                              void* d_out, int out_size, void* d_ws, size_t ws_size,
                              hipStream_t stream) {
  const float* u = (const float*)d_in[0];
  const float* alpha_base = (const float*)d_in[1];
  const float* beta_base = (const float*)d_in[2];
  const float* alpha_spatial = (const float*)d_in[3];
  const float* beta_spatial = (const float*)d_in[4];
  const float* coupling = (const float*)d_in[5];
  float* out = (float*)d_out;
  float* ws = (float*)d_ws;

  means_part<<<96, 256, 0, stream>>>(alpha_spatial, beta_spatial, ws);
  coeff_kernel<<<1, 64, 0, stream>>>(alpha_base, beta_base, ws);
  fused3<<<NPLANE * 4, 1024, 0, stream>>>(u, out, ws, coupling);
}

// Round 6
// 179.245 us; speedup vs baseline: 1.4297x; 1.4297x over previous
//
#include <hip/hip_runtime.h>

// Problem constants (fixed by setup_inputs)
constexpr int Bn = 128, Cn = 3, Sn = 256;
constexpr int HWn = Sn * Sn;          // 65536
constexpr int NPLANE = Bn * Cn;       // 384
constexpr float DTf = 0.05f;
constexpr float EPSf = 1e-6f;
constexpr float MAXCf = 1.0f;

// ws float layout:
//   [8..25]     r[step][dir][c] (18)
//   [32..127]   means partials (6 groups x 16 blocks)
//   [128..]     cp tables [18][256] (cp[255] = TRUE value)
//   [4736..]    dinv tables [18][256]
#define WS_R    8
#define WS_PART 32
#define WS_CP   128
#define WS_DINV 4736

__global__ void means_part(const float* __restrict__ aspat,
                           const float* __restrict__ bspat,
                           float* __restrict__ ws) {
  int grp = blockIdx.x >> 4;   // 0..5 = dir*3 + c
  int sub = blockIdx.x & 15;
  const float* base = (grp < 3) ? (aspat + grp * HWn) : (bspat + (grp - 3) * HWn);
  const float4* p = (const float4*)base + sub * 1024 + threadIdx.x;
  double acc = 0.0;
#pragma unroll
  for (int k = 0; k < 4; ++k) {
    float4 v = p[k * 256];
    acc += (double)v.x + (double)v.y + (double)v.z + (double)v.w;
  }
  __shared__ double sm[256];
  sm[threadIdx.x] = acc;
  __syncthreads();
  for (int s = 128; s > 0; s >>= 1) {
    if (threadIdx.x < s) sm[threadIdx.x] += sm[threadIdx.x + s];
    __syncthreads();
  }
  if (threadIdx.x == 0) ws[WS_PART + blockIdx.x] = (float)sm[0];
}

// One thread per (step, dir, channel): build cp[256], dinv[256], r.
__global__ void coeff_kernel(const float* __restrict__ alpha_base,
                             const float* __restrict__ beta_base,
                             float* __restrict__ ws) {
  int id = threadIdx.x;
  if (id >= 18) return;
  int s = id / 6, dir = (id / 3) % 2, c = id % 3;
  double msum = 0.0;
  for (int k = 0; k < 16; ++k) msum += (double)ws[WS_PART + (dir * 3 + c) * 16 + k];
  float mean = (float)(msum * (1.0 / HWn));
  float t = (float)s * DTf;
  float base = (dir == 0) ? alpha_base[c] : beta_base[c];
  float coef = fminf(fmaxf(base + mean * t, EPSf), MAXCf);
  float r = coef * (DTf * 0.5f);  // DX = 1
  ws[WS_R + id] = r;
  float* cp = ws + WS_CP + id * 256;
  float* dinv = ws + WS_DINV + id * 256;
  float b0 = 1.0f + r;
  float bi = 1.0f + 2.0f * r;
  dinv[0] = 1.0f / (b0 + EPSf);
  cp[0] = -r / (b0 + EPSf);
  for (int i = 1; i < 256; ++i) {
    float b = (i == 255) ? b0 : bi;
    float denom = fmaxf(b + r * cp[i - 1], EPSf);  // b - a*cp_prev, a=-r
    cp[i] = -r / denom;
    dinv[i] = 1.0f / denom;
  }
  // cp[255] TRUE: forward uses -cp[i]==r*dinv[i] at all i; back-substitution
  // never multiplies cp[255] (x_255 = dp_255 explicitly).
}

// ------------- Fully-fused kernel: 3 ADI steps (6 solves) in one pass -------
// Block = (plane, stripe): 112-row x 256-col LDS window, core 64 rows.
// Validity shrinks 8/side per y-solve (halo-truncation, err ~0.0075^9).
// diag(coupling) applied to the field at the END of EVERY step.
// LDS swizzle (involution, quad-granular): (row,col) at word
//   rl*256 + ((colq ^ (rl&7))<<2 | col&3).   a0 = 0 mod 8 for all stripes.
__global__ __launch_bounds__(512, 2) void fused3(
    const float* __restrict__ src, float* __restrict__ dst,
    const float* __restrict__ ws, const float* __restrict__ coupling) {
  __shared__ float tile[112 * 256];          // 114688 B
  __shared__ float4 s_cx[3][64];             // x cp   per step
  __shared__ float4 s_dx[3][64];             // x dinv per step
  __shared__ float2 s_cdy[3][256];           // y (cp, dinv) interleaved
  __shared__ float s_diag;

  const int t = threadIdx.x;
  // XCD-bijective swizzle: 1536 = 8*192; same-plane stripes -> same XCD.
  const int logical = (blockIdx.x & 7) * 192 + (blockIdx.x >> 3);
  const int plane = logical >> 2;            // b*3 + c
  const int s = logical & 3;                 // stripe
  const int c = plane % 3;

  const int a0 = (s == 0) ? 0 : s * 64 - 24; // 0,40,104,168 (all = 0 mod 8)
  const int b0 = (s == 3) ? 256 : s * 64 + 88;
  const int W = b0 - a0;                     // 112 interior, 88 edges

  // ---- DMA: wave wv loads rows [16wv,16wv+16) — the SAME rows it x0-solves
  const float* srcp = src + (size_t)plane * HWn;
  {
    const int wv = t >> 6, l = t & 63;
#pragma unroll
    for (int kk = 0; kk < 16; ++kk) {
      const int rl = wv * 16 + kk;
      if (rl < W) {
        const float* gp = srcp + (size_t)(a0 + rl) * 256 + ((l ^ (rl & 7)) << 2);
        __builtin_amdgcn_global_load_lds(
            (const __attribute__((address_space(1))) void*)gp,
            (__attribute__((address_space(3))) void*)(tile + rl * 256), 16, 0, 0);
      }
    }
  }

  // ---- coefficient tables -> LDS ----
  if (t < 384) {                             // x tables: 6 x 64 float4
    const int tab = t >> 6, q = t & 63;
    if (tab < 3)
      s_cx[tab][q] = ((const float4*)(ws + WS_CP + (size_t)(6 * tab + c) * 256))[q];
    else
      s_dx[tab - 3][q] = ((const float4*)(ws + WS_DINV + (size_t)(6 * (tab - 3) + c) * 256))[q];
  }
  if (t < 384) {                             // y tables: 3 x 128 float4 (pairs)
    const int ky = t >> 7, pr = t & 127;
    const float2 cp2 = ((const float2*)(ws + WS_CP + (size_t)(6 * ky + 3 + c) * 256))[pr];
    const float2 di2 = ((const float2*)(ws + WS_DINV + (size_t)(6 * ky + 3 + c) * 256))[pr];
    ((float4*)s_cdy[ky])[pr] = make_float4(cp2.x, di2.x, cp2.y, di2.y);
  }
  if (t == 448) s_diag = coupling[c * 3 + c];

  // Barrier for tables only (lgkm); DMA stays in flight (per-wave vmcnt later).
  asm volatile("s_waitcnt lgkmcnt(0)" ::: "memory");
  __builtin_amdgcn_s_barrier();
  __builtin_amdgcn_sched_barrier(0);

#pragma unroll
  for (int k = 0; k < 3; ++k) {
    // ================= x-solve (row-local, all W rows) =================
    {
      if (k == 0) asm volatile("s_waitcnt vmcnt(0)" ::: "memory");  // own rows
      const int rw = t >> 2, cw = t & 3;
      if (rw < W) {
        // 20-quad window, core 16 quads [16cw,16cw+16) at rel [off,off+16)
        const int off = (cw == 0) ? 0 : ((cw == 3) ? 4 : 2);
        const int qs = 16 * cw - off;
        const int sw = rw & 7;
        float4* trow = (float4*)tile + rw * 64;
        const float4* cp4 = s_cx[k];
        const float4* di4 = s_dx[k];
        float4 dq[20];
        float prev = 0.0f;                   // exact at col 0; halo-trunc else
#pragma unroll
        for (int i = 0; i < 20; ++i) {
          const int q = qs + i;
          float4 v = trow[q ^ sw];
          float4 cq = cp4[q];
          float4 eq = di4[q];
          float d0 = fmaf(-cq.x, prev, v.x * eq.x);
          float d1 = fmaf(-cq.y, d0, v.y * eq.y);
          float d2 = fmaf(-cq.z, d1, v.z * eq.z);
          float d3 = fmaf(-cq.w, d2, v.w * eq.w);
          dq[i] = make_float4(d0, d1, d2, d3);
          prev = d3;
        }
        float x = 0.0f;
#pragma unroll
        for (int i = 19; i >= 0; --i) {
          const int q = qs + i;
          float4 v = dq[i];
          float4 cq = cp4[q];
          float x3 = (i == 19) ? v.w : fmaf(-cq.w, x, v.w);
          float x2 = fmaf(-cq.z, x3, v.z);
          float x1 = fmaf(-cq.y, x2, v.y);
          float x0 = fmaf(-cq.x, x1, v.x);
          if (i >= off && i < off + 16) trow[q ^ sw] = make_float4(x0, x1, x2, x3);
          x = x0;
        }
      }
      __syncthreads();
    }
    // ======== y-solve: 2 segs x UNIFORM 64-row windows, zero clamping ======
    {
      const int col = t & 255, seg = t >> 8;  // wave-uniform seg
      const int av = (s == 0) ? 0 : a0 + 8 * k;        // valid band
      const int bv = (s == 3) ? 256 : b0 - 8 * k;
      const int o0 = (s == 0) ? 0 : a0 + 8 * (k + 1);  // output cores
      const int o1 = (s == 3) ? 256 : b0 - 8 * (k + 1);
      const int clen = (o1 - o0) >> 1;
      const int c0 = o0 + seg * clen;
      const int c1 = (seg == 0) ? (o0 + clen) : o1;
      const int hs = seg ? (bv - 64) : av;    // anchored, = 0 mod 8
      const int rl0 = hs - a0;                // = 0 mod 8
      const int jq = col >> 2, jr = col & 3;
      float* bp[8];                           // unrolled-const indexed only
#pragma unroll
      for (int p = 0; p < 8; ++p)
        bp[p] = tile + (rl0 + p) * 256 + (((jq ^ p) << 2) | jr);
      const float2* cdp = s_cdy[k] + hs;
      float dp[64];
      float prev = 0.0f;                      // exact at row 0; halo-trunc else
#pragma unroll
      for (int o = 0; o < 8; ++o) {
#pragma unroll
        for (int p = 0; p < 8; ++p) {
          const int i = 8 * o + p;
          const float2 cd = cdp[i];           // (cp, dinv) broadcast
          const float v = bp[p][o * 2048];
          prev = fmaf(-cd.x, prev, v * cd.y);
          dp[i] = prev;
        }
      }
      __syncthreads();                        // all fwd reads before bwd writes
      const int wlo = c0 - hs, whi = c1 - hs;
      const float dg = s_diag;
      float x = 0.0f;
      if (k == 2) {
        float* dstp = dst + (size_t)plane * HWn + (size_t)hs * 256 + col;
#pragma unroll
        for (int i = 63; i >= 0; --i) {
          x = (i == 63) ? dp[63] : fmaf(-cdp[i].x, x, dp[i]);
          if (i >= wlo && i < whi) dstp[(size_t)i * 256] = x * dg;
        }
      } else {
#pragma unroll
        for (int o = 7; o >= 0; --o) {
#pragma unroll
          for (int p = 7; p >= 0; --p) {
            const int i = 8 * o + p;
            x = (i == 63) ? dp[63] : fmaf(-cdp[i].x, x, dp[i]);
            if (i >= wlo && i < whi) bp[p][o * 2048] = x * dg;
          }
        }
        __syncthreads();
      }
    }
  }
}

extern "C" void kernel_launch(void* const* d_in, const int* in_sizes, int n_in,
                              void* d_out, int out_size, void* d_ws, size_t ws_size,
                              hipStream_t stream) {
  const float* u = (const float*)d_in[0];
  const float* alpha_base = (const float*)d_in[1];
  const float* beta_base = (const float*)d_in[2];
  const float* alpha_spatial = (const float*)d_in[3];
  const float* beta_spatial = (const float*)d_in[4];
  const float* coupling = (const float*)d_in[5];
  float* out = (float*)d_out;
  float* ws = (float*)d_ws;

  means_part<<<96, 256, 0, stream>>>(alpha_spatial, beta_spatial, ws);
  coeff_kernel<<<1, 64, 0, stream>>>(alpha_base, beta_base, ws);
  fused3<<<NPLANE * 4, 512, 0, stream>>>(u, out, ws, coupling);
}